// Round 1
// baseline (4775.723 us; speedup 1.0000x reference)
//
#include <hip/hip_runtime.h>

#define N_TOT 50500
#define E_NUM 800000
#define D_IN_ 100
#define D_HID 200
#define ALPHA 0.2f
#define EPS_ 1e-12f

// ---------------------------------------------------------------------------
// Tiled fp32 GEMM: C[N,M] = A[N,K] @ B[K,M]. 64x64 tile, BK=16, 256 threads,
// 4x4 microtile per thread. Handles ragged N/M/K with bounds checks.
// ---------------------------------------------------------------------------
__global__ __launch_bounds__(256) void gemm_kernel(
    const float* __restrict__ A, const float* __restrict__ B,
    float* __restrict__ C, int Nn, int K, int M) {
  __shared__ float As[16][65];  // [k][row], +1 pad
  __shared__ float Bs[16][65];  // [k][col], +1 pad
  const int tid = threadIdx.x;
  const int tx = tid & 15;      // col group 0..15
  const int ty = tid >> 4;      // row group 0..15
  const int rowBase = blockIdx.x * 64;
  const int colBase = blockIdx.y * 64;

  float acc[4][4] = {};

  for (int k0 = 0; k0 < K; k0 += 16) {
#pragma unroll
    for (int i = 0; i < 4; ++i) {
      int idx = tid + i * 256;          // 0..1023
      // A tile: kk fastest -> coalesced 16-float row segments
      int ar = idx >> 4;                // 0..63 row in tile
      int ak = idx & 15;                // 0..15
      int gr = rowBase + ar, gk = k0 + ak;
      As[ak][ar] = (gr < Nn && gk < K) ? A[(long)gr * K + gk] : 0.f;
      // B tile: col fastest -> coalesced 64-float segments
      int bc = idx & 63;                // 0..63 col in tile
      int bk = idx >> 6;                // 0..15
      int gc = colBase + bc, gk2 = k0 + bk;
      Bs[bk][bc] = (gc < M && gk2 < K) ? B[(long)gk2 * M + gc] : 0.f;
    }
    __syncthreads();
#pragma unroll
    for (int kk = 0; kk < 16; ++kk) {
      float a[4], b[4];
#pragma unroll
      for (int i = 0; i < 4; ++i) a[i] = As[kk][ty + i * 16];
#pragma unroll
      for (int j = 0; j < 4; ++j) b[j] = Bs[kk][tx + j * 16];
#pragma unroll
      for (int i = 0; i < 4; ++i)
#pragma unroll
        for (int j = 0; j < 4; ++j) acc[i][j] += a[i] * b[j];
    }
    __syncthreads();
  }

#pragma unroll
  for (int i = 0; i < 4; ++i) {
    int gr = rowBase + ty + i * 16;
    if (gr >= Nn) continue;
#pragma unroll
    for (int j = 0; j < 4; ++j) {
      int gc = colBase + tx + j * 16;
      if (gc < M) C[(long)gr * M + gc] = acc[i][j];
    }
  }
}

// ---------------------------------------------------------------------------
// Edge scatter: for each edge e, agg[dst[e]] += h[src[e]] * vals[e].
// One thread per (edge, 4-float chunk); 50 chunks cover D_HID=200.
// ---------------------------------------------------------------------------
__global__ __launch_bounds__(256) void scatter_kernel(
    const float* __restrict__ h, const int* __restrict__ src,
    const int* __restrict__ dst, const float* __restrict__ vals,
    float* __restrict__ agg) {
  long tid = (long)blockIdx.x * blockDim.x + threadIdx.x;
  const long total = (long)E_NUM * 50;
  if (tid >= total) return;
  int e = (int)(tid / 50);
  int c = (int)(tid % 50);
  int s = src[e];
  int d = dst[e];
  float v = vals[e];
  const float4 hv =
      *reinterpret_cast<const float4*>(h + (long)s * D_HID + c * 4);
  float* out = agg + (long)d * D_HID + c * 4;
  atomicAdd(out + 0, hv.x * v);
  atomicAdd(out + 1, hv.y * v);
  atomicAdd(out + 2, hv.z * v);
  atomicAdd(out + 3, hv.w * v);
}

// ---------------------------------------------------------------------------
// In-place LeakyReLU over n4 float4s.
// ---------------------------------------------------------------------------
__global__ __launch_bounds__(256) void lrelu_kernel(float* __restrict__ x,
                                                    long n4) {
  long i = (long)blockIdx.x * blockDim.x + threadIdx.x;
  if (i >= n4) return;
  float4 v = reinterpret_cast<float4*>(x)[i];
  v.x = v.x > 0.f ? v.x : ALPHA * v.x;
  v.y = v.y > 0.f ? v.y : ALPHA * v.y;
  v.z = v.z > 0.f ? v.z : ALPHA * v.z;
  v.w = v.w > 0.f ? v.w : ALPHA * v.w;
  reinterpret_cast<float4*>(x)[i] = v;
}

// ---------------------------------------------------------------------------
// Fused LeakyReLU + L2 row-normalize, in place. One wave (64 lanes) per row;
// lanes 0..49 each own one float4 (200 floats/row).
// ---------------------------------------------------------------------------
__global__ __launch_bounds__(256) void norm_kernel(float* __restrict__ x) {
  const int wave = threadIdx.x >> 6;
  const int lane = threadIdx.x & 63;
  const int row = blockIdx.x * 4 + wave;
  if (row >= N_TOT) return;
  float* p = x + (long)row * D_HID;
  float4 v = {0.f, 0.f, 0.f, 0.f};
  if (lane < 50) {
    v = *reinterpret_cast<float4*>(p + lane * 4);
    v.x = v.x > 0.f ? v.x : ALPHA * v.x;
    v.y = v.y > 0.f ? v.y : ALPHA * v.y;
    v.z = v.z > 0.f ? v.z : ALPHA * v.z;
    v.w = v.w > 0.f ? v.w : ALPHA * v.w;
  }
  float ss = v.x * v.x + v.y * v.y + v.z * v.z + v.w * v.w;
#pragma unroll
  for (int off = 32; off; off >>= 1) ss += __shfl_xor(ss, off);
  float inv = 1.f / fmaxf(sqrtf(ss), EPS_);
  if (lane < 50) {
    float4 o = {v.x * inv, v.y * inv, v.z * inv, v.w * inv};
    *reinterpret_cast<float4*>(p + lane * 4) = o;
  }
}

// ---------------------------------------------------------------------------
extern "C" void kernel_launch(void* const* d_in, const int* in_sizes, int n_in,
                              void* d_out, int out_size, void* d_ws,
                              size_t ws_size, hipStream_t stream) {
  const float* emb = (const float*)d_in[0];   // [N_TOT, 100]
  const float* W1 = (const float*)d_in[1];    // [100, 200]
  const float* W2 = (const float*)d_in[2];    // [200, 200]
  const int* eidx = (const int*)d_in[3];      // [2, E] row-major
  const float* vals = (const float*)d_in[4];  // [E]
  const int* src = eidx;
  const int* dst = eidx + E_NUM;
  float* out = (float*)d_out;                 // [N_TOT, 200] flat

  const size_t bufBytes =
      (((size_t)N_TOT * D_HID * sizeof(float)) + 255) & ~(size_t)255;
  float* projBuf = (float*)d_ws;                        // projection h = x@W
  float* h1Buf = (float*)((char*)d_ws + bufBytes);      // agg1 -> h1

  dim3 gemmGrid((N_TOT + 63) / 64, (D_HID + 63) / 64);
  const long scatterItems = (long)E_NUM * 50;
  const int scatterBlocks = (int)((scatterItems + 255) / 256);
  const long n4 = (long)N_TOT * D_HID / 4;

  // ---- layer 1 ----
  hipMemsetAsync(h1Buf, 0, (size_t)N_TOT * D_HID * sizeof(float), stream);
  gemm_kernel<<<gemmGrid, 256, 0, stream>>>(emb, W1, projBuf, N_TOT, D_IN_,
                                            D_HID);
  scatter_kernel<<<scatterBlocks, 256, 0, stream>>>(projBuf, src, dst, vals,
                                                    h1Buf);
  lrelu_kernel<<<(int)((n4 + 255) / 256), 256, 0, stream>>>(h1Buf, n4);

  // ---- layer 2 (aggregate directly into d_out) ----
  hipMemsetAsync(out, 0, (size_t)N_TOT * D_HID * sizeof(float), stream);
  gemm_kernel<<<gemmGrid, 256, 0, stream>>>(h1Buf, W2, projBuf, N_TOT, D_HID,
                                            D_HID);
  scatter_kernel<<<scatterBlocks, 256, 0, stream>>>(projBuf, src, dst, vals,
                                                    out);

  // ---- fused LeakyReLU + L2 normalize, in place on d_out ----
  norm_kernel<<<(N_TOT + 3) / 4, 256, 0, stream>>>(out);
}

// Round 5
// 569.058 us; speedup vs baseline: 8.3923x; 8.3923x over previous
//
#include <hip/hip_runtime.h>

#define N_TOT 50500
#define E_NUM 800000
#define D_IN_ 100
#define D_HID 200
#define ALPHA 0.2f
#define EPS_ 1e-12f
#define SCAN_B 256
#define NBLK_SCAN ((N_TOT + SCAN_B - 1) / SCAN_B)  // 198

// ---------------------------------------------------------------------------
// Tiled fp32 GEMM: C[N,M] = A[N,K] @ B[K,M]. 64x64 tile, BK=16, 256 threads,
// 4x4 microtile per thread.
// ---------------------------------------------------------------------------
__global__ __launch_bounds__(256) void gemm_kernel(
    const float* __restrict__ A, const float* __restrict__ B,
    float* __restrict__ C, int Nn, int K, int M) {
  __shared__ float As[16][65];
  __shared__ float Bs[16][65];
  const int tid = threadIdx.x;
  const int tx = tid & 15;
  const int ty = tid >> 4;
  const int rowBase = blockIdx.x * 64;
  const int colBase = blockIdx.y * 64;

  float acc[4][4] = {};

  for (int k0 = 0; k0 < K; k0 += 16) {
#pragma unroll
    for (int i = 0; i < 4; ++i) {
      int idx = tid + i * 256;
      int ar = idx >> 4;
      int ak = idx & 15;
      int gr = rowBase + ar, gk = k0 + ak;
      As[ak][ar] = (gr < Nn && gk < K) ? A[(long)gr * K + gk] : 0.f;
      int bc = idx & 63;
      int bk = idx >> 6;
      int gc = colBase + bc, gk2 = k0 + bk;
      Bs[bk][bc] = (gc < M && gk2 < K) ? B[(long)gk2 * M + gc] : 0.f;
    }
    __syncthreads();
#pragma unroll
    for (int kk = 0; kk < 16; ++kk) {
      float a[4], b[4];
#pragma unroll
      for (int i = 0; i < 4; ++i) a[i] = As[kk][ty + i * 16];
#pragma unroll
      for (int j = 0; j < 4; ++j) b[j] = Bs[kk][tx + j * 16];
#pragma unroll
      for (int i = 0; i < 4; ++i)
#pragma unroll
        for (int j = 0; j < 4; ++j) acc[i][j] += a[i] * b[j];
    }
    __syncthreads();
  }

#pragma unroll
  for (int i = 0; i < 4; ++i) {
    int gr = rowBase + ty + i * 16;
    if (gr >= Nn) continue;
#pragma unroll
    for (int j = 0; j < 4; ++j) {
      int gc = colBase + tx + j * 16;
      if (gc < M) C[(long)gr * M + gc] = acc[i][j];
    }
  }
}

// ---------------------------------------------------------------------------
// CSR build: histogram -> 3-kernel exclusive scan -> fill.
// ---------------------------------------------------------------------------
__global__ __launch_bounds__(256) void hist_kernel(const int* __restrict__ dst,
                                                   int* __restrict__ counts) {
  int e = blockIdx.x * blockDim.x + threadIdx.x;
  if (e < E_NUM) atomicAdd(&counts[dst[e]], 1);
}

__global__ __launch_bounds__(SCAN_B) void scan1_kernel(
    const int* __restrict__ counts, int* __restrict__ starts,
    int* __restrict__ blockSums) {
  __shared__ int s[SCAN_B];
  int i = blockIdx.x * SCAN_B + threadIdx.x;
  int v = (i < N_TOT) ? counts[i] : 0;
  s[threadIdx.x] = v;
  __syncthreads();
  for (int off = 1; off < SCAN_B; off <<= 1) {
    int t = (threadIdx.x >= off) ? s[threadIdx.x - off] : 0;
    __syncthreads();
    s[threadIdx.x] += t;
    __syncthreads();
  }
  if (i < N_TOT) starts[i] = s[threadIdx.x] - v;
  if (threadIdx.x == SCAN_B - 1) blockSums[blockIdx.x] = s[threadIdx.x];
}

__global__ __launch_bounds__(SCAN_B) void scan2_kernel(
    int* __restrict__ blockSums) {
  __shared__ int s[SCAN_B];
  int v = (threadIdx.x < NBLK_SCAN) ? blockSums[threadIdx.x] : 0;
  s[threadIdx.x] = v;
  __syncthreads();
  for (int off = 1; off < SCAN_B; off <<= 1) {
    int t = (threadIdx.x >= off) ? s[threadIdx.x - off] : 0;
    __syncthreads();
    s[threadIdx.x] += t;
    __syncthreads();
  }
  if (threadIdx.x < NBLK_SCAN) blockSums[threadIdx.x] = s[threadIdx.x] - v;
}

__global__ __launch_bounds__(SCAN_B) void scan3_kernel(
    int* __restrict__ starts, const int* __restrict__ blockSums,
    int* __restrict__ cursor) {
  int i = blockIdx.x * SCAN_B + threadIdx.x;
  if (i < N_TOT) {
    int st = starts[i] + blockSums[blockIdx.x];
    starts[i] = st;
    cursor[i] = st;
  }
}

__global__ __launch_bounds__(256) void fill_kernel(
    const int* __restrict__ src, const int* __restrict__ dst,
    const float* __restrict__ vals, int* __restrict__ cursor,
    int* __restrict__ csrSrc, float* __restrict__ csrVal) {
  int e = blockIdx.x * blockDim.x + threadIdx.x;
  if (e >= E_NUM) return;
  int d = dst[e];
  int pos = atomicAdd(&cursor[d], 1);
  csrSrc[pos] = src[e];
  csrVal[pos] = vals[e];
}

// ---------------------------------------------------------------------------
// Pull-mode aggregation: one wave per row. Lanes 0..49 own one float4 each of
// the 200-wide row. acc = sum_j h[src_j] * val_j, then LeakyReLU; FINAL also
// L2-normalizes (wave shfl reduce) before the single non-atomic row write.
// ---------------------------------------------------------------------------
template <bool FINAL>
__global__ __launch_bounds__(256) void agg_kernel(
    const float* __restrict__ h, const int* __restrict__ starts,
    const int* __restrict__ counts, const int* __restrict__ csrSrc,
    const float* __restrict__ csrVal, float* __restrict__ out) {
  const int wave = threadIdx.x >> 6;
  const int lane = threadIdx.x & 63;
  const int row = blockIdx.x * 4 + wave;
  if (row >= N_TOT) return;
  const int st = starts[row];
  const int cnt = counts[row];
  const float4* __restrict__ h4 = reinterpret_cast<const float4*>(h);

  float4 acc = {0.f, 0.f, 0.f, 0.f};
  int j = 0;
  for (; j + 1 < cnt; j += 2) {
    int s0 = csrSrc[st + j], s1 = csrSrc[st + j + 1];
    float v0 = csrVal[st + j], v1 = csrVal[st + j + 1];
    if (lane < 50) {
      float4 a = h4[(long)s0 * 50 + lane];
      float4 b = h4[(long)s1 * 50 + lane];
      acc.x += a.x * v0 + b.x * v1;
      acc.y += a.y * v0 + b.y * v1;
      acc.z += a.z * v0 + b.z * v1;
      acc.w += a.w * v0 + b.w * v1;
    }
  }
  if (j < cnt) {
    int s0 = csrSrc[st + j];
    float v0 = csrVal[st + j];
    if (lane < 50) {
      float4 a = h4[(long)s0 * 50 + lane];
      acc.x += a.x * v0;
      acc.y += a.y * v0;
      acc.z += a.z * v0;
      acc.w += a.w * v0;
    }
  }

  // LeakyReLU
  acc.x = acc.x > 0.f ? acc.x : ALPHA * acc.x;
  acc.y = acc.y > 0.f ? acc.y : ALPHA * acc.y;
  acc.z = acc.z > 0.f ? acc.z : ALPHA * acc.z;
  acc.w = acc.w > 0.f ? acc.w : ALPHA * acc.w;

  if (FINAL) {
    float ss =
        acc.x * acc.x + acc.y * acc.y + acc.z * acc.z + acc.w * acc.w;
#pragma unroll
    for (int off = 32; off; off >>= 1) ss += __shfl_xor(ss, off);
    float inv = 1.f / fmaxf(sqrtf(ss), EPS_);
    acc.x *= inv;
    acc.y *= inv;
    acc.z *= inv;
    acc.w *= inv;
  }

  if (lane < 50) reinterpret_cast<float4*>(out)[(long)row * 50 + lane] = acc;
}

// ---------------------------------------------------------------------------
extern "C" void kernel_launch(void* const* d_in, const int* in_sizes, int n_in,
                              void* d_out, int out_size, void* d_ws,
                              size_t ws_size, hipStream_t stream) {
  const float* emb = (const float*)d_in[0];   // [N_TOT, 100]
  const float* W1 = (const float*)d_in[1];    // [100, 200]
  const float* W2 = (const float*)d_in[2];    // [200, 200]
  const int* eidx = (const int*)d_in[3];      // [2, E] (int32 per harness)
  const float* vals = (const float*)d_in[4];  // [E]
  const int* src = eidx;
  const int* dst = eidx + E_NUM;
  float* out = (float*)d_out;                 // [N_TOT, 200] flat

  // ---- workspace layout (~47.9 MB total; h1 lives in d_out) ----
  char* p = (char*)d_ws;
  auto take = [&](size_t bytes) {
    char* r = p;
    p += (bytes + 255) & ~(size_t)255;
    return r;
  };
  float* projBuf = (float*)take((size_t)N_TOT * D_HID * sizeof(float));
  int* csrSrc = (int*)take((size_t)E_NUM * sizeof(int));
  float* csrVal = (float*)take((size_t)E_NUM * sizeof(float));
  int* counts = (int*)take((size_t)N_TOT * sizeof(int));
  int* starts = (int*)take((size_t)N_TOT * sizeof(int));
  int* cursor = (int*)take((size_t)N_TOT * sizeof(int));
  int* blockSums = (int*)take((size_t)NBLK_SCAN * sizeof(int));

  const int eBlocks = (E_NUM + 255) / 256;

  // ---- CSR build (once; shared by both layers) ----
  hipMemsetAsync(counts, 0, (size_t)N_TOT * sizeof(int), stream);
  hist_kernel<<<eBlocks, 256, 0, stream>>>(dst, counts);
  scan1_kernel<<<NBLK_SCAN, SCAN_B, 0, stream>>>(counts, starts, blockSums);
  scan2_kernel<<<1, SCAN_B, 0, stream>>>(blockSums);
  scan3_kernel<<<NBLK_SCAN, SCAN_B, 0, stream>>>(starts, blockSums, cursor);
  fill_kernel<<<eBlocks, 256, 0, stream>>>(src, dst, vals, cursor, csrSrc,
                                           csrVal);

  dim3 gemmGrid((N_TOT + 63) / 64, (D_HID + 63) / 64);
  const int aggBlocks = (N_TOT + 3) / 4;

  // ---- layer 1 (h1 aggregated into d_out, used as scratch) ----
  gemm_kernel<<<gemmGrid, 256, 0, stream>>>(emb, W1, projBuf, N_TOT, D_IN_,
                                            D_HID);
  agg_kernel<false><<<aggBlocks, 256, 0, stream>>>(projBuf, starts, counts,
                                                   csrSrc, csrVal, out);

  // ---- layer 2 (reads h1 from d_out, re-projects, aggregates back into
  //      d_out with fused LeakyReLU + L2 normalize; stream-serialized) ----
  gemm_kernel<<<gemmGrid, 256, 0, stream>>>(out, W2, projBuf, N_TOT, D_HID,
                                            D_HID);
  agg_kernel<true><<<aggBlocks, 256, 0, stream>>>(projBuf, starts, counts,
                                                  csrSrc, csrVal, out);
}

// Round 7
// 511.271 us; speedup vs baseline: 9.3409x; 1.1130x over previous
//
#include <hip/hip_runtime.h>

#define N_TOT 50500
#define E_NUM 800000
#define D_IN_ 100
#define D_HID 200
#define ALPHA 0.2f
#define EPS_ 1e-12f
#define SCAN_B 256
#define NBLK_SCAN ((N_TOT + SCAN_B - 1) / SCAN_B)  // 198
#define LDP 68  // padded LDS leading dim: 68*4B = 272 = 17*16 -> b128-aligned

// ---------------------------------------------------------------------------
// Tiled fp32 GEMM: C[N,M] = A[N,K] @ B[K,M]. 64x64 tile, BK=16, 256 threads.
// Thread owns a CONTIGUOUS 4x4 microtile (rows ty*4.., cols tx*4..) so each
// kk needs just 2 ds_read_b128. LDS is k-major [16][68]. Grid is (Mtiles,
// Ntiles) so consecutive blocks share the A row-tile (L2 reuse).
// ---------------------------------------------------------------------------
__global__ __launch_bounds__(256) void gemm_kernel(
    const float* __restrict__ A, const float* __restrict__ B,
    float* __restrict__ C, int Nn, int K, int M) {
  __shared__ float As[16][LDP];  // [k][row]
  __shared__ float Bs[16][LDP];  // [k][col]
  const int tid = threadIdx.x;
  const int tx = tid & 15;   // col group: cols tx*4..tx*4+3
  const int ty = tid >> 4;   // row group: rows ty*4..ty*4+3
  const int colBase = blockIdx.x * 64;
  const int rowBase = blockIdx.y * 64;

  // staging coords
  const int sar = tid >> 2;          // A: row 0..63
  const int sak = (tid & 3) * 4;     // A: k offset (float4 of k)
  const int sbk = tid >> 4;          // B: k 0..15
  const int sbc = (tid & 15) * 4;    // B: col offset (float4 of cols)

  float acc[4][4] = {};

  for (int k0 = 0; k0 < K; k0 += 16) {
    // ---- stage A tile: 64 rows x 16 k, one float4 of k per thread ----
    {
      float4 v = {0.f, 0.f, 0.f, 0.f};
      int gr = rowBase + sar;
      int gk = k0 + sak;
      if (gr < Nn) {
        if (gk + 3 < K) {
          v = *reinterpret_cast<const float4*>(A + (long)gr * K + gk);
        } else {
          float t0 = (gk + 0 < K) ? A[(long)gr * K + gk + 0] : 0.f;
          float t1 = (gk + 1 < K) ? A[(long)gr * K + gk + 1] : 0.f;
          float t2 = (gk + 2 < K) ? A[(long)gr * K + gk + 2] : 0.f;
          float t3 = (gk + 3 < K) ? A[(long)gr * K + gk + 3] : 0.f;
          v = {t0, t1, t2, t3};
        }
      }
      As[sak + 0][sar] = v.x;
      As[sak + 1][sar] = v.y;
      As[sak + 2][sar] = v.z;
      As[sak + 3][sar] = v.w;
    }
    // ---- stage B tile: 16 k x 64 cols, one float4 of cols per thread ----
    {
      float4 v = {0.f, 0.f, 0.f, 0.f};
      int gk = k0 + sbk;
      int gc = colBase + sbc;
      if (gk < K) {
        if (gc + 3 < M) {
          v = *reinterpret_cast<const float4*>(B + (long)gk * M + gc);
        } else {
          float t0 = (gc + 0 < M) ? B[(long)gk * M + gc + 0] : 0.f;
          float t1 = (gc + 1 < M) ? B[(long)gk * M + gc + 1] : 0.f;
          float t2 = (gc + 2 < M) ? B[(long)gk * M + gc + 2] : 0.f;
          float t3 = (gc + 3 < M) ? B[(long)gk * M + gc + 3] : 0.f;
          v = {t0, t1, t2, t3};
        }
      }
      *reinterpret_cast<float4*>(&Bs[sbk][sbc]) = v;
    }
    __syncthreads();

#pragma unroll
    for (int kk = 0; kk < 16; ++kk) {
      float4 a = *reinterpret_cast<const float4*>(&As[kk][ty * 4]);
      float4 b = *reinterpret_cast<const float4*>(&Bs[kk][tx * 4]);
      acc[0][0] += a.x * b.x; acc[0][1] += a.x * b.y;
      acc[0][2] += a.x * b.z; acc[0][3] += a.x * b.w;
      acc[1][0] += a.y * b.x; acc[1][1] += a.y * b.y;
      acc[1][2] += a.y * b.z; acc[1][3] += a.y * b.w;
      acc[2][0] += a.z * b.x; acc[2][1] += a.z * b.y;
      acc[2][2] += a.z * b.z; acc[2][3] += a.z * b.w;
      acc[3][0] += a.w * b.x; acc[3][1] += a.w * b.y;
      acc[3][2] += a.w * b.z; acc[3][3] += a.w * b.w;
    }
    __syncthreads();
  }

  // ---- write C: 4 rows, one float4 of cols each (M % 4 == 0) ----
  const int gc = colBase + tx * 4;
  if (gc + 3 < M) {
#pragma unroll
    for (int i = 0; i < 4; ++i) {
      int gr = rowBase + ty * 4 + i;
      if (gr < Nn) {
        float4 o = {acc[i][0], acc[i][1], acc[i][2], acc[i][3]};
        *reinterpret_cast<float4*>(C + (long)gr * M + gc) = o;
      }
    }
  }
}

// ---------------------------------------------------------------------------
// CSR build: histogram -> 3-kernel exclusive scan -> fill. (unchanged)
// ---------------------------------------------------------------------------
__global__ __launch_bounds__(256) void hist_kernel(const int* __restrict__ dst,
                                                   int* __restrict__ counts) {
  int e = blockIdx.x * blockDim.x + threadIdx.x;
  if (e < E_NUM) atomicAdd(&counts[dst[e]], 1);
}

__global__ __launch_bounds__(SCAN_B) void scan1_kernel(
    const int* __restrict__ counts, int* __restrict__ starts,
    int* __restrict__ blockSums) {
  __shared__ int s[SCAN_B];
  int i = blockIdx.x * SCAN_B + threadIdx.x;
  int v = (i < N_TOT) ? counts[i] : 0;
  s[threadIdx.x] = v;
  __syncthreads();
  for (int off = 1; off < SCAN_B; off <<= 1) {
    int t = (threadIdx.x >= off) ? s[threadIdx.x - off] : 0;
    __syncthreads();
    s[threadIdx.x] += t;
    __syncthreads();
  }
  if (i < N_TOT) starts[i] = s[threadIdx.x] - v;
  if (threadIdx.x == SCAN_B - 1) blockSums[blockIdx.x] = s[threadIdx.x];
}

__global__ __launch_bounds__(SCAN_B) void scan2_kernel(
    int* __restrict__ blockSums) {
  __shared__ int s[SCAN_B];
  int v = (threadIdx.x < NBLK_SCAN) ? blockSums[threadIdx.x] : 0;
  s[threadIdx.x] = v;
  __syncthreads();
  for (int off = 1; off < SCAN_B; off <<= 1) {
    int t = (threadIdx.x >= off) ? s[threadIdx.x - off] : 0;
    __syncthreads();
    s[threadIdx.x] += t;
    __syncthreads();
  }
  if (threadIdx.x < NBLK_SCAN) blockSums[threadIdx.x] = s[threadIdx.x] - v;
}

__global__ __launch_bounds__(SCAN_B) void scan3_kernel(
    int* __restrict__ starts, const int* __restrict__ blockSums,
    int* __restrict__ cursor) {
  int i = blockIdx.x * SCAN_B + threadIdx.x;
  if (i < N_TOT) {
    int st = starts[i] + blockSums[blockIdx.x];
    starts[i] = st;
    cursor[i] = st;
  }
}

__global__ __launch_bounds__(256) void fill_kernel(
    const int* __restrict__ src, const int* __restrict__ dst,
    const float* __restrict__ vals, int* __restrict__ cursor,
    int* __restrict__ csrSrc, float* __restrict__ csrVal) {
  int e = blockIdx.x * blockDim.x + threadIdx.x;
  if (e >= E_NUM) return;
  int d = dst[e];
  int pos = atomicAdd(&cursor[d], 1);
  csrSrc[pos] = src[e];
  csrVal[pos] = vals[e];
}

// ---------------------------------------------------------------------------
// Pull-mode aggregation: one wave per row. (unchanged from R4 — it passed;
// its counters will surface in the next profile now that GEMM is faster)
// ---------------------------------------------------------------------------
template <bool FINAL>
__global__ __launch_bounds__(256) void agg_kernel(
    const float* __restrict__ h, const int* __restrict__ starts,
    const int* __restrict__ counts, const int* __restrict__ csrSrc,
    const float* __restrict__ csrVal, float* __restrict__ out) {
  const int wave = threadIdx.x >> 6;
  const int lane = threadIdx.x & 63;
  const int row = blockIdx.x * 4 + wave;
  if (row >= N_TOT) return;
  const int st = starts[row];
  const int cnt = counts[row];
  const float4* __restrict__ h4 = reinterpret_cast<const float4*>(h);

  float4 acc = {0.f, 0.f, 0.f, 0.f};
  int j = 0;
  for (; j + 1 < cnt; j += 2) {
    int s0 = csrSrc[st + j], s1 = csrSrc[st + j + 1];
    float v0 = csrVal[st + j], v1 = csrVal[st + j + 1];
    if (lane < 50) {
      float4 a = h4[(long)s0 * 50 + lane];
      float4 b = h4[(long)s1 * 50 + lane];
      acc.x += a.x * v0 + b.x * v1;
      acc.y += a.y * v0 + b.y * v1;
      acc.z += a.z * v0 + b.z * v1;
      acc.w += a.w * v0 + b.w * v1;
    }
  }
  if (j < cnt) {
    int s0 = csrSrc[st + j];
    float v0 = csrVal[st + j];
    if (lane < 50) {
      float4 a = h4[(long)s0 * 50 + lane];
      acc.x += a.x * v0;
      acc.y += a.y * v0;
      acc.z += a.z * v0;
      acc.w += a.w * v0;
    }
  }

  // LeakyReLU
  acc.x = acc.x > 0.f ? acc.x : ALPHA * acc.x;
  acc.y = acc.y > 0.f ? acc.y : ALPHA * acc.y;
  acc.z = acc.z > 0.f ? acc.z : ALPHA * acc.z;
  acc.w = acc.w > 0.f ? acc.w : ALPHA * acc.w;

  if (FINAL) {
    float ss =
        acc.x * acc.x + acc.y * acc.y + acc.z * acc.z + acc.w * acc.w;
#pragma unroll
    for (int off = 32; off; off >>= 1) ss += __shfl_xor(ss, off);
    float inv = 1.f / fmaxf(sqrtf(ss), EPS_);
    acc.x *= inv;
    acc.y *= inv;
    acc.z *= inv;
    acc.w *= inv;
  }

  if (lane < 50) reinterpret_cast<float4*>(out)[(long)row * 50 + lane] = acc;
}

// ---------------------------------------------------------------------------
extern "C" void kernel_launch(void* const* d_in, const int* in_sizes, int n_in,
                              void* d_out, int out_size, void* d_ws,
                              size_t ws_size, hipStream_t stream) {
  const float* emb = (const float*)d_in[0];   // [N_TOT, 100]
  const float* W1 = (const float*)d_in[1];    // [100, 200]
  const float* W2 = (const float*)d_in[2];    // [200, 200]
  const int* eidx = (const int*)d_in[3];      // [2, E]
  const float* vals = (const float*)d_in[4];  // [E]
  const int* src = eidx;
  const int* dst = eidx + E_NUM;
  float* out = (float*)d_out;                 // [N_TOT, 200] flat

  // ---- workspace layout (~47.9 MB total; h1 lives in d_out) ----
  char* p = (char*)d_ws;
  auto take = [&](size_t bytes) {
    char* r = p;
    p += (bytes + 255) & ~(size_t)255;
    return r;
  };
  float* projBuf = (float*)take((size_t)N_TOT * D_HID * sizeof(float));
  int* csrSrc = (int*)take((size_t)E_NUM * sizeof(int));
  float* csrVal = (float*)take((size_t)E_NUM * sizeof(float));
  int* counts = (int*)take((size_t)N_TOT * sizeof(int));
  int* starts = (int*)take((size_t)N_TOT * sizeof(int));
  int* cursor = (int*)take((size_t)N_TOT * sizeof(int));
  int* blockSums = (int*)take((size_t)NBLK_SCAN * sizeof(int));

  const int eBlocks = (E_NUM + 255) / 256;

  // ---- CSR build (once; shared by both layers) ----
  hipMemsetAsync(counts, 0, (size_t)N_TOT * sizeof(int), stream);
  hist_kernel<<<eBlocks, 256, 0, stream>>>(dst, counts);
  scan1_kernel<<<NBLK_SCAN, SCAN_B, 0, stream>>>(counts, starts, blockSums);
  scan2_kernel<<<1, SCAN_B, 0, stream>>>(blockSums);
  scan3_kernel<<<NBLK_SCAN, SCAN_B, 0, stream>>>(starts, blockSums, cursor);
  fill_kernel<<<eBlocks, 256, 0, stream>>>(src, dst, vals, cursor, csrSrc,
                                           csrVal);

  // grid: x = col tiles (fast) so consecutive blocks reuse the A row-tile
  dim3 gemmGrid((D_HID + 63) / 64, (N_TOT + 63) / 64);
  const int aggBlocks = (N_TOT + 3) / 4;

  // ---- layer 1 (h1 aggregated into d_out, used as scratch) ----
  gemm_kernel<<<gemmGrid, 256, 0, stream>>>(emb, W1, projBuf, N_TOT, D_IN_,
                                            D_HID);
  agg_kernel<false><<<aggBlocks, 256, 0, stream>>>(projBuf, starts, counts,
                                                   csrSrc, csrVal, out);

  // ---- layer 2 (reads h1 from d_out, aggregates back into d_out) ----
  gemm_kernel<<<gemmGrid, 256, 0, stream>>>(out, W2, projBuf, N_TOT, D_HID,
                                            D_HID);
  agg_kernel<true><<<aggBlocks, 256, 0, stream>>>(projBuf, starts, counts,
                                                  csrSrc, csrVal, out);
}

// Round 8
// 483.747 us; speedup vs baseline: 9.8724x; 1.0569x over previous
//
#include <hip/hip_runtime.h>

#define N_TOT 50500
#define E_NUM 800000
#define D_IN_ 100
#define D_HID 200
#define ALPHA 0.2f
#define EPS_ 1e-12f
#define SCAN_B 256
#define NBLK_SCAN ((N_TOT + SCAN_B - 1) / SCAN_B)  // 198
#define LDP2 132  // 132*4B = 528 = 33*16 -> float4-aligned rows, odd/16 stride

// ---------------------------------------------------------------------------
// 128x128-tile fp32 GEMM, BK=8, 256 threads, 8x8 split microtile per thread
// (2x2 blocks of 4x4 at offsets {0,64}): per kk, 4 ds_read_b128 (<=2-way
// bank alias, free) feed 64 FMAs. Optional fused LeakyReLU epilogue.
// ---------------------------------------------------------------------------
__device__ __forceinline__ void fma4x4(float (&c)[16], const float4& a,
                                       const float4& b) {
  c[0] += a.x * b.x;  c[1] += a.x * b.y;  c[2] += a.x * b.z;  c[3] += a.x * b.w;
  c[4] += a.y * b.x;  c[5] += a.y * b.y;  c[6] += a.y * b.z;  c[7] += a.y * b.w;
  c[8] += a.z * b.x;  c[9] += a.z * b.y;  c[10] += a.z * b.z; c[11] += a.z * b.w;
  c[12] += a.w * b.x; c[13] += a.w * b.y; c[14] += a.w * b.z; c[15] += a.w * b.w;
}

template <bool LRELU>
__global__ __launch_bounds__(256) void gemm128_kernel(
    const float* __restrict__ A, const float* __restrict__ B,
    float* __restrict__ C, int Nn, int K, int M) {
  __shared__ float As[8][LDP2];  // [k][row]
  __shared__ float Bs[8][LDP2];  // [k][col]
  const int tid = threadIdx.x;
  const int tx = tid & 15;   // cols tx*4..+3 and 64+tx*4..+3
  const int ty = tid >> 4;   // rows ty*4..+3 and 64+ty*4..+3
  const int colBase = blockIdx.x * 128;
  const int rowBase = blockIdx.y * 128;

  // staging coords
  const int sar = tid >> 1;        // A: row 0..127
  const int sak = (tid & 1) * 4;   // A: k offset 0 or 4
  const int sbk = tid >> 5;        // B: k 0..7
  const int sbc = (tid & 31) * 4;  // B: col 0..124

  float acc[2][2][16] = {};

  for (int k0 = 0; k0 < K; k0 += 8) {
    // ---- stage A: 128 rows x 8 k ----
    {
      float4 v = {0.f, 0.f, 0.f, 0.f};
      int gr = rowBase + sar;
      int gk = k0 + sak;
      if (gr < Nn) {
        if (gk + 3 < K) {
          v = *reinterpret_cast<const float4*>(A + (long)gr * K + gk);
        } else {
          v.x = (gk + 0 < K) ? A[(long)gr * K + gk + 0] : 0.f;
          v.y = (gk + 1 < K) ? A[(long)gr * K + gk + 1] : 0.f;
          v.z = (gk + 2 < K) ? A[(long)gr * K + gk + 2] : 0.f;
          v.w = (gk + 3 < K) ? A[(long)gr * K + gk + 3] : 0.f;
        }
      }
      As[sak + 0][sar] = v.x;
      As[sak + 1][sar] = v.y;
      As[sak + 2][sar] = v.z;
      As[sak + 3][sar] = v.w;
    }
    // ---- stage B: 8 k x 128 cols ----
    {
      float4 v = {0.f, 0.f, 0.f, 0.f};
      int gk = k0 + sbk;
      int gc = colBase + sbc;
      if (gk < K) {
        if (gc + 3 < M) {
          v = *reinterpret_cast<const float4*>(B + (long)gk * M + gc);
        } else {
          v.x = (gc + 0 < M) ? B[(long)gk * M + gc + 0] : 0.f;
          v.y = (gc + 1 < M) ? B[(long)gk * M + gc + 1] : 0.f;
          v.z = (gc + 2 < M) ? B[(long)gk * M + gc + 2] : 0.f;
          v.w = (gc + 3 < M) ? B[(long)gk * M + gc + 3] : 0.f;
        }
      }
      *reinterpret_cast<float4*>(&Bs[sbk][sbc]) = v;
    }
    __syncthreads();

#pragma unroll
    for (int kk = 0; kk < 8; ++kk) {
      float4 a0 = *reinterpret_cast<const float4*>(&As[kk][ty * 4]);
      float4 a1 = *reinterpret_cast<const float4*>(&As[kk][64 + ty * 4]);
      float4 b0 = *reinterpret_cast<const float4*>(&Bs[kk][tx * 4]);
      float4 b1 = *reinterpret_cast<const float4*>(&Bs[kk][64 + tx * 4]);
      fma4x4(acc[0][0], a0, b0);
      fma4x4(acc[0][1], a0, b1);
      fma4x4(acc[1][0], a1, b0);
      fma4x4(acc[1][1], a1, b1);
    }
    __syncthreads();
  }

  // ---- write C (M % 4 == 0; per-float4 col bounds) ----
#pragma unroll
  for (int rh = 0; rh < 2; ++rh) {
#pragma unroll
    for (int i = 0; i < 4; ++i) {
      int gr = rowBase + rh * 64 + ty * 4 + i;
      if (gr >= Nn) continue;
#pragma unroll
      for (int ch = 0; ch < 2; ++ch) {
        int gc = colBase + ch * 64 + tx * 4;
        if (gc + 3 < M) {
          float4 o = {acc[rh][ch][i * 4 + 0], acc[rh][ch][i * 4 + 1],
                      acc[rh][ch][i * 4 + 2], acc[rh][ch][i * 4 + 3]};
          if (LRELU) {
            o.x = o.x > 0.f ? o.x : ALPHA * o.x;
            o.y = o.y > 0.f ? o.y : ALPHA * o.y;
            o.z = o.z > 0.f ? o.z : ALPHA * o.z;
            o.w = o.w > 0.f ? o.w : ALPHA * o.w;
          }
          *reinterpret_cast<float4*>(C + (long)gr * M + gc) = o;
        }
      }
    }
  }
}

// ---------------------------------------------------------------------------
// CSR build: histogram -> 3-kernel exclusive scan -> fill. (unchanged)
// ---------------------------------------------------------------------------
__global__ __launch_bounds__(256) void hist_kernel(const int* __restrict__ dst,
                                                   int* __restrict__ counts) {
  int e = blockIdx.x * blockDim.x + threadIdx.x;
  if (e < E_NUM) atomicAdd(&counts[dst[e]], 1);
}

__global__ __launch_bounds__(SCAN_B) void scan1_kernel(
    const int* __restrict__ counts, int* __restrict__ starts,
    int* __restrict__ blockSums) {
  __shared__ int s[SCAN_B];
  int i = blockIdx.x * SCAN_B + threadIdx.x;
  int v = (i < N_TOT) ? counts[i] : 0;
  s[threadIdx.x] = v;
  __syncthreads();
  for (int off = 1; off < SCAN_B; off <<= 1) {
    int t = (threadIdx.x >= off) ? s[threadIdx.x - off] : 0;
    __syncthreads();
    s[threadIdx.x] += t;
    __syncthreads();
  }
  if (i < N_TOT) starts[i] = s[threadIdx.x] - v;
  if (threadIdx.x == SCAN_B - 1) blockSums[blockIdx.x] = s[threadIdx.x];
}

__global__ __launch_bounds__(SCAN_B) void scan2_kernel(
    int* __restrict__ blockSums) {
  __shared__ int s[SCAN_B];
  int v = (threadIdx.x < NBLK_SCAN) ? blockSums[threadIdx.x] : 0;
  s[threadIdx.x] = v;
  __syncthreads();
  for (int off = 1; off < SCAN_B; off <<= 1) {
    int t = (threadIdx.x >= off) ? s[threadIdx.x - off] : 0;
    __syncthreads();
    s[threadIdx.x] += t;
    __syncthreads();
  }
  if (threadIdx.x < NBLK_SCAN) blockSums[threadIdx.x] = s[threadIdx.x] - v;
}

__global__ __launch_bounds__(SCAN_B) void scan3_kernel(
    int* __restrict__ starts, const int* __restrict__ blockSums,
    int* __restrict__ cursor) {
  int i = blockIdx.x * SCAN_B + threadIdx.x;
  if (i < N_TOT) {
    int st = starts[i] + blockSums[blockIdx.x];
    starts[i] = st;
    cursor[i] = st;
  }
}

__global__ __launch_bounds__(256) void fill_kernel(
    const int* __restrict__ src, const int* __restrict__ dst,
    const float* __restrict__ vals, int* __restrict__ cursor,
    int* __restrict__ csrSrc, float* __restrict__ csrVal) {
  int e = blockIdx.x * blockDim.x + threadIdx.x;
  if (e >= E_NUM) return;
  int d = dst[e];
  int pos = atomicAdd(&cursor[d], 1);
  csrSrc[pos] = src[e];
  csrVal[pos] = vals[e];
}

// ---------------------------------------------------------------------------
// Pure pull aggregation (no epilogue — nonlinearities moved after the GEMM
// by linearity of segment_sum). One wave per row; lanes < CHUNKS own one
// float4 each; 4x-unrolled edge loop for gather MLP.
// ---------------------------------------------------------------------------
template <int CHUNKS>
__global__ __launch_bounds__(256) void agg_kernel(
    const float* __restrict__ h, const int* __restrict__ starts,
    const int* __restrict__ counts, const int* __restrict__ csrSrc,
    const float* __restrict__ csrVal, float* __restrict__ out) {
  const int wave = threadIdx.x >> 6;
  const int lane = threadIdx.x & 63;
  const int row = blockIdx.x * 4 + wave;
  if (row >= N_TOT) return;
  const int st = starts[row];
  const int cnt = counts[row];
  const float4* __restrict__ h4 = reinterpret_cast<const float4*>(h);

  float4 acc = {0.f, 0.f, 0.f, 0.f};
  int j = 0;
  for (; j + 3 < cnt; j += 4) {
    int s0 = csrSrc[st + j + 0], s1 = csrSrc[st + j + 1];
    int s2 = csrSrc[st + j + 2], s3 = csrSrc[st + j + 3];
    float v0 = csrVal[st + j + 0], v1 = csrVal[st + j + 1];
    float v2 = csrVal[st + j + 2], v3 = csrVal[st + j + 3];
    if (lane < CHUNKS) {
      float4 a = h4[(long)s0 * CHUNKS + lane];
      float4 b = h4[(long)s1 * CHUNKS + lane];
      float4 c = h4[(long)s2 * CHUNKS + lane];
      float4 d = h4[(long)s3 * CHUNKS + lane];
      acc.x += a.x * v0 + b.x * v1 + c.x * v2 + d.x * v3;
      acc.y += a.y * v0 + b.y * v1 + c.y * v2 + d.y * v3;
      acc.z += a.z * v0 + b.z * v1 + c.z * v2 + d.z * v3;
      acc.w += a.w * v0 + b.w * v1 + c.w * v2 + d.w * v3;
    }
  }
  for (; j < cnt; ++j) {
    int s0 = csrSrc[st + j];
    float v0 = csrVal[st + j];
    if (lane < CHUNKS) {
      float4 a = h4[(long)s0 * CHUNKS + lane];
      acc.x += a.x * v0;
      acc.y += a.y * v0;
      acc.z += a.z * v0;
      acc.w += a.w * v0;
    }
  }
  if (lane < CHUNKS)
    reinterpret_cast<float4*>(out)[(long)row * CHUNKS + lane] = acc;
}

// ---------------------------------------------------------------------------
// Fused LeakyReLU + L2 row-normalize, in place (R0's known-good kernel).
// ---------------------------------------------------------------------------
__global__ __launch_bounds__(256) void norm_kernel(float* __restrict__ x) {
  const int wave = threadIdx.x >> 6;
  const int lane = threadIdx.x & 63;
  const int row = blockIdx.x * 4 + wave;
  if (row >= N_TOT) return;
  float* p = x + (long)row * D_HID;
  float4 v = {0.f, 0.f, 0.f, 0.f};
  if (lane < 50) {
    v = *reinterpret_cast<float4*>(p + lane * 4);
    v.x = v.x > 0.f ? v.x : ALPHA * v.x;
    v.y = v.y > 0.f ? v.y : ALPHA * v.y;
    v.z = v.z > 0.f ? v.z : ALPHA * v.z;
    v.w = v.w > 0.f ? v.w : ALPHA * v.w;
  }
  float ss = v.x * v.x + v.y * v.y + v.z * v.z + v.w * v.w;
#pragma unroll
  for (int off = 32; off; off >>= 1) ss += __shfl_xor(ss, off);
  float inv = 1.f / fmaxf(sqrtf(ss), EPS_);
  if (lane < 50) {
    float4 o = {v.x * inv, v.y * inv, v.z * inv, v.w * inv};
    *reinterpret_cast<float4*>(p + lane * 4) = o;
  }
}

// ---------------------------------------------------------------------------
extern "C" void kernel_launch(void* const* d_in, const int* in_sizes, int n_in,
                              void* d_out, int out_size, void* d_ws,
                              size_t ws_size, hipStream_t stream) {
  const float* emb = (const float*)d_in[0];   // [N_TOT, 100]
  const float* W1 = (const float*)d_in[1];    // [100, 200]
  const float* W2 = (const float*)d_in[2];    // [200, 200]
  const int* eidx = (const int*)d_in[3];      // [2, E]
  const float* vals = (const float*)d_in[4];  // [E]
  const int* src = eidx;
  const int* dst = eidx + E_NUM;
  float* out = (float*)d_out;                 // [N_TOT, 200] flat

  // ---- workspace layout (~68 MB; R0 proved ws >= ~81 MB) ----
  char* p = (char*)d_ws;
  auto take = [&](size_t bytes) {
    char* r = p;
    p += (bytes + 255) & ~(size_t)255;
    return r;
  };
  float* g1 = (float*)take((size_t)N_TOT * D_IN_ * sizeof(float));   // 20.2 MB
  float* g2 = (float*)take((size_t)N_TOT * D_HID * sizeof(float));   // 40.4 MB
  int* csrSrc = (int*)take((size_t)E_NUM * sizeof(int));
  float* csrVal = (float*)take((size_t)E_NUM * sizeof(float));
  int* counts = (int*)take((size_t)N_TOT * sizeof(int));
  int* starts = (int*)take((size_t)N_TOT * sizeof(int));
  int* cursor = (int*)take((size_t)N_TOT * sizeof(int));
  int* blockSums = (int*)take((size_t)NBLK_SCAN * sizeof(int));

  const int eBlocks = (E_NUM + 255) / 256;
  const int rowWaveBlocks = (N_TOT + 3) / 4;

  // ---- CSR build (once; shared by both layers) ----
  hipMemsetAsync(counts, 0, (size_t)N_TOT * sizeof(int), stream);
  hist_kernel<<<eBlocks, 256, 0, stream>>>(dst, counts);
  scan1_kernel<<<NBLK_SCAN, SCAN_B, 0, stream>>>(counts, starts, blockSums);
  scan2_kernel<<<1, SCAN_B, 0, stream>>>(blockSums);
  scan3_kernel<<<NBLK_SCAN, SCAN_B, 0, stream>>>(starts, blockSums, cursor);
  fill_kernel<<<eBlocks, 256, 0, stream>>>(src, dst, vals, cursor, csrSrc,
                                           csrVal);

  dim3 gemmGrid((D_HID + 127) / 128, (N_TOT + 127) / 128);  // (2, 395)

  // ---- layer 1: aggregate emb in 100-dim, then project (+lrelu) ----
  //      (segsum commutes with the right-multiply: exact linearity)
  agg_kernel<25><<<rowWaveBlocks, 256, 0, stream>>>(emb, starts, counts,
                                                    csrSrc, csrVal, g1);
  gemm128_kernel<true><<<gemmGrid, 256, 0, stream>>>(g1, W1, out /*h1*/,
                                                     N_TOT, D_IN_, D_HID);

  // ---- layer 2: aggregate h1, project, then lrelu+normalize ----
  agg_kernel<50><<<rowWaveBlocks, 256, 0, stream>>>(out, starts, counts,
                                                    csrSrc, csrVal, g2);
  gemm128_kernel<false><<<gemmGrid, 256, 0, stream>>>(g2, W2, out, N_TOT,
                                                      D_HID, D_HID);
  norm_kernel<<<rowWaveBlocks, 256, 0, stream>>>(out);
}